// Round 1
// baseline (697.122 us; speedup 1.0000x reference)
//
#include <hip/hip_runtime.h>
#include <math.h>

#define N_CELLS 16384
#define HID 512
#define IND 512
#define KNB 15
#define NCOPY 64

// ---- workspace layout (bytes) ----
#define VAR_OFF   0                                   // double[2]: sum(a), sum(a^2)
#define NLAS_OFF  16                                  // int: n_lasing
#define EMIS_OFF  128                                 // float[NCOPY][1024]: emission partials (re[512], im[512])
#define LAS_OFF   (EMIS_OFF + NCOPY*1024*4)           // int[N_CELLS]: lasing flags
#define CAV_OFF   (LAS_OFF + N_CELLS*4)               // float[1536]: cav_new_re[512], cav_new_im[512], cav_phase[512]
#define ROT_OFF   (1<<20)                             // float2[N_CELLS*HID]: rotated states
#define NST_OFF   (ROT_OFF + (size_t)N_CELLS*HID*8)   // float2[N_CELLS*HID]: new_states (pre-lock)

// ---------------------------------------------------------------------------
// Kernel 1: pump = sigmoid(x . pump_W[i] + pump_b[i]); excited update; lasing
// One wave (64 lanes) per cell.
__global__ __launch_bounds__(256) void k_pump(const float* __restrict__ x,
                                              const float* __restrict__ pW,
                                              const float* __restrict__ pb,
                                              const float* __restrict__ excited,
                                              int* __restrict__ lasing,
                                              int* __restrict__ nlas) {
    int gtid = blockIdx.x * 256 + threadIdx.x;
    int cell = gtid >> 6;
    int lane = gtid & 63;
    const float4* w4 = (const float4*)(pW + (size_t)cell * IND);
    const float4* x4 = (const float4*)x;
    float acc = 0.f;
#pragma unroll
    for (int t = 0; t < (IND / 4) / 64; ++t) {     // 2 iters
        float4 a = w4[lane + 64 * t];
        float4 b = x4[lane + 64 * t];
        acc += a.x * b.x + a.y * b.y + a.z * b.z + a.w * b.w;
    }
#pragma unroll
    for (int o = 32; o; o >>= 1) acc += __shfl_xor(acc, o, 64);
    if (lane == 0) {
        float p = 1.f / (1.f + expf(-(acc + pb[cell])));
        float e = excited[cell] * 0.95f + p * 0.05f;
        e = fminf(fmaxf(e, 0.f), 1.f);
        int las = (e > 0.5f) ? 1 : 0;
        lasing[cell] = las;
        if (las) atomicAdd(nlas, 1);
    }
}

// ---------------------------------------------------------------------------
// Kernel 2: rotate states by exp(i * 0.1 * phase_vel). 4 elems/thread.
__global__ __launch_bounds__(256) void k_rot(const float* __restrict__ cr,
                                             const float* __restrict__ ci,
                                             const float* __restrict__ pv,
                                             float2* __restrict__ rot) {
    int i = blockIdx.x * 256 + threadIdx.x;        // over N*H/4
    const float4* cr4 = (const float4*)cr;
    const float4* ci4 = (const float4*)ci;
    const float4* pv4 = (const float4*)pv;
    float4 a = cr4[i], b = ci4[i], t = pv4[i];
    float s0, c0, s1, c1, s2, c2, s3, c3;
    __sincosf(0.1f * t.x, &s0, &c0);
    __sincosf(0.1f * t.y, &s1, &c1);
    __sincosf(0.1f * t.z, &s2, &c2);
    __sincosf(0.1f * t.w, &s3, &c3);
    float4 o0 = make_float4(a.x * c0 - b.x * s0, a.x * s0 + b.x * c0,
                            a.y * c1 - b.y * s1, a.y * s1 + b.y * c1);
    float4 o1 = make_float4(a.z * c2 - b.z * s2, a.z * s2 + b.z * c2,
                            a.w * c3 - b.w * s3, a.w * s3 + b.w * c3);
    float4* r4 = (float4*)rot;
    r4[2 * i]     = o0;
    r4[2 * i + 1] = o1;
}

// ---------------------------------------------------------------------------
// Kernel 3: neighbor coupling + new_states + emission partials.
// One block per cell, 512 threads (one per h-channel).
// coupling*nb_state = ((s_i . s_nb)/(|s_i||s_nb|)) * s_nb  -- no atan2 needed.
__global__ __launch_bounds__(512) void k_coup(const float2* __restrict__ rot,
                                              const int* __restrict__ nbrs,
                                              const int* __restrict__ lasing,
                                              float2* __restrict__ nst,
                                              float* __restrict__ emis) {
    __shared__ int nb[KNB];
    __shared__ int las;
    int cell = blockIdx.x;
    int c = threadIdx.x;
    if (c < KNB) nb[c] = nbrs[cell * KNB + c];
    if (c == KNB) las = lasing[cell];
    __syncthreads();

    float2 s = rot[(size_t)cell * HID + c];
    float rinv = rsqrtf(s.x * s.x + s.y * s.y);
    float ar = 0.f, ai = 0.f;
#pragma unroll
    for (int t = 0; t < KNB; ++t) {
        float2 q = rot[(size_t)nb[t] * HID + c];
        float d = s.x * q.x + s.y * q.y;
        float qinv = rsqrtf(q.x * q.x + q.y * q.y);
        float w = d * rinv * qinv;                 // cos(ang_i - ang_nb)
        ar = fmaf(w, q.x, ar);
        ai = fmaf(w, q.y, ai);
    }
    // new = 0.7*s + (0.3*0.1/15) * sum
    float nr = 0.7f * s.x + 0.002f * ar;
    float ni = 0.7f * s.y + 0.002f * ai;
    nst[(size_t)cell * HID + c] = make_float2(nr, ni);
    if (las) {
        float* em = emis + (size_t)(cell & (NCOPY - 1)) * 1024;
        atomicAdd(em + c, nr);
        atomicAdd(em + 512 + c, ni);
    }
}

// ---------------------------------------------------------------------------
// Kernel 4: reduce emission copies; cavity_new; cavity_phase (OLD cavity).
__global__ __launch_bounds__(512) void k_cav(const float* __restrict__ emis,
                                             const int* __restrict__ nlas,
                                             const float* __restrict__ cavr,
                                             const float* __restrict__ cavi,
                                             float* __restrict__ cav) {
    int c = threadIdx.x;
    float er = 0.f, ei = 0.f;
    for (int k = 0; k < NCOPY; ++k) {
        er += emis[k * 1024 + c];
        ei += emis[k * 1024 + 512 + c];
    }
    int nl = *nlas;
    float cr = cavr[c], ci = cavi[c];
    float nr, ni;
    if (nl > 0) {
        float inv = 1.f / (float)(nl > 1 ? nl : 1);
        nr = 0.8f * cr + 0.2f * er * inv;
        ni = 0.8f * ci + 0.2f * ei * inv;
    } else {
        nr = cr;
        ni = ci;
    }
    cav[c] = nr;
    cav[512 + c] = ni;
    cav[1024 + c] = atan2f(ci, cr);                // old cavity phase
}

// ---------------------------------------------------------------------------
// Kernel 5: pred = [cav_new.re, cav_new.im] @ dec_W.T + dec_b. Wave per row.
__global__ __launch_bounds__(512) void k_pred(const float* __restrict__ cav,
                                              const float* __restrict__ dW,
                                              const float* __restrict__ db,
                                              float* __restrict__ out) {
    int gtid = blockIdx.x * 512 + threadIdx.x;
    int j = gtid >> 6;                             // 512 waves -> 512 outputs
    int lane = gtid & 63;
    const float4* w4 = (const float4*)(dW + (size_t)j * (2 * HID));
    const float4* o4 = (const float4*)cav;         // first 1024 floats = out_real
    float acc = 0.f;
#pragma unroll
    for (int t = 0; t < (2 * HID / 4) / 64; ++t) { // 4 iters
        float4 a = w4[lane + 64 * t];
        float4 b = o4[lane + 64 * t];
        acc += a.x * b.x + a.y * b.y + a.z * b.z + a.w * b.w;
    }
#pragma unroll
    for (int o = 32; o; o >>= 1) acc += __shfl_xor(acc, o, 64);
    if (lane == 0) out[j] = acc + db[j];
}

// ---------------------------------------------------------------------------
// Kernel 6: phase-lock lasing cells, add cavity feedback, row-max renorm,
// accumulate variance sums. Block per cell.
__global__ __launch_bounds__(512) void k_fin(const float2* __restrict__ nst,
                                             const int* __restrict__ lasing,
                                             const float* __restrict__ cav,
                                             double* __restrict__ vacc) {
    __shared__ float sred[8];
    __shared__ float sbc;
    int cell = blockIdx.x;
    int c = threadIdx.x;
    int wid = c >> 6, lane = c & 63;
    int las = lasing[cell];

    float2 v = nst[(size_t)cell * HID + c];
    if (las) {
        float r = sqrtf(v.x * v.x + v.y * v.y);
        float ang = atan2f(v.y, v.x);
        float locked = 0.3f * cav[1024 + c] + 0.7f * ang;
        float sn, cs;
        __sincosf(locked, &sn, &cs);
        v = make_float2(r * cs, r * sn);
    }
    v.x += 0.05f * cav[c];
    v.y += 0.05f * cav[512 + c];
    float amp = sqrtf(v.x * v.x + v.y * v.y);

    // block max
    float m = amp;
#pragma unroll
    for (int o = 32; o; o >>= 1) m = fmaxf(m, __shfl_xor(m, o, 64));
    if (lane == 0) sred[wid] = m;
    __syncthreads();
    if (c == 0) {
        float mm = sred[0];
        for (int k = 1; k < 8; ++k) mm = fmaxf(mm, sred[k]);
        sbc = mm;
    }
    __syncthreads();
    float a = amp / (sbc + 1e-8f);

    // block sums of a and a^2
    float s1 = a, s2 = a * a;
#pragma unroll
    for (int o = 32; o; o >>= 1) { s1 += __shfl_xor(s1, o, 64); s2 += __shfl_xor(s2, o, 64); }
    __shared__ float w1[8], w2[8];
    if (lane == 0) { w1[wid] = s1; w2[wid] = s2; }
    __syncthreads();
    if (c == 0) {
        float t1 = 0.f, t2 = 0.f;
        for (int k = 0; k < 8; ++k) { t1 += w1[k]; t2 += w2[k]; }
        atomicAdd(vacc, (double)t1);
        atomicAdd(vacc + 1, (double)t2);
    }
}

// ---------------------------------------------------------------------------
// Kernel 7: tension = E[a^2] - E[a]^2
__global__ void k_var(const double* __restrict__ vacc, float* __restrict__ out) {
    double n = (double)N_CELLS * (double)HID;
    double mean = vacc[0] / n;
    out[IND] = (float)(vacc[1] / n - mean * mean);
}

// ---------------------------------------------------------------------------
extern "C" void kernel_launch(void* const* d_in, const int* in_sizes, int n_in,
                              void* d_out, int out_size, void* d_ws, size_t ws_size,
                              hipStream_t stream) {
    const float* x       = (const float*)d_in[0];
    const float* pump_W  = (const float*)d_in[1];
    const float* pump_b  = (const float*)d_in[2];
    const float* dec_W   = (const float*)d_in[3];
    const float* dec_b   = (const float*)d_in[4];
    const float* cs_re   = (const float*)d_in[5];
    const float* cs_im   = (const float*)d_in[6];
    const float* excited = (const float*)d_in[7];
    const float* pvel    = (const float*)d_in[8];
    const float* cav_re  = (const float*)d_in[9];
    const float* cav_im  = (const float*)d_in[10];
    const int*   nbrs    = (const int*)d_in[11];

    float* out = (float*)d_out;
    char* ws = (char*)d_ws;
    double* vacc  = (double*)(ws + VAR_OFF);
    int*    nlas  = (int*)(ws + NLAS_OFF);
    float*  emis  = (float*)(ws + EMIS_OFF);
    int*    lasv  = (int*)(ws + LAS_OFF);
    float*  cav   = (float*)(ws + CAV_OFF);
    float2* rot   = (float2*)(ws + ROT_OFF);
    float2* nst   = (float2*)(ws + NST_OFF);

    // zero accumulators (ws is poisoned 0xAA before every launch)
    hipMemsetAsync(ws, 0, EMIS_OFF + NCOPY * 1024 * 4, stream);

    k_pump<<<N_CELLS / 4, 256, 0, stream>>>(x, pump_W, pump_b, excited, lasv, nlas);
    k_rot<<<(N_CELLS * HID / 4) / 256, 256, 0, stream>>>(cs_re, cs_im, pvel, rot);
    k_coup<<<N_CELLS, 512, 0, stream>>>(rot, nbrs, lasv, nst, emis);
    k_cav<<<1, 512, 0, stream>>>(emis, nlas, cav_re, cav_im, cav);
    k_pred<<<64, 512, 0, stream>>>(cav, dec_W, dec_b, out);
    k_fin<<<N_CELLS, 512, 0, stream>>>(nst, lasv, cav, vacc);
    k_var<<<1, 1, 0, stream>>>(vacc, out);
}

// Round 2
// 337.876 us; speedup vs baseline: 2.0632x; 2.0632x over previous
//
#include <hip/hip_runtime.h>
#include <math.h>

#define N_CELLS 16384
#define HID 512
#define IND 512
#define KNB 15
#define NCOPY 64

// ---- workspace layout (bytes) ----
#define NLAS_OFF  16                                  // int: n_lasing
#define EMIS_OFF  128                                 // float[NCOPY][1024]: emission partials (re[512], im[512])
#define LAS_OFF   (EMIS_OFF + NCOPY*1024*4)           // int[N_CELLS]: lasing flags
#define CAV_OFF   (LAS_OFF + N_CELLS*4)               // float[1536]: cav_new_re[512], cav_new_im[512], cav_phase[512]
#define VPART_OFF (CAV_OFF + 1536*4)                  // float2[N_CELLS]: per-cell (sum_a, sum_a2) partials
#define ROT_OFF   (1<<20)                             // float2[N_CELLS*HID]: rotated states
#define NST_OFF   (ROT_OFF + (size_t)N_CELLS*HID*8)   // float2[N_CELLS*HID]: new_states (pre-lock)

// ---------------------------------------------------------------------------
// Kernel 1: pump = sigmoid(x . pump_W[i] + pump_b[i]); excited update; lasing
// One wave (64 lanes) per cell.
__global__ __launch_bounds__(256) void k_pump(const float* __restrict__ x,
                                              const float* __restrict__ pW,
                                              const float* __restrict__ pb,
                                              const float* __restrict__ excited,
                                              int* __restrict__ lasing,
                                              int* __restrict__ nlas) {
    int gtid = blockIdx.x * 256 + threadIdx.x;
    int cell = gtid >> 6;
    int lane = gtid & 63;
    const float4* w4 = (const float4*)(pW + (size_t)cell * IND);
    const float4* x4 = (const float4*)x;
    float acc = 0.f;
#pragma unroll
    for (int t = 0; t < (IND / 4) / 64; ++t) {     // 2 iters
        float4 a = w4[lane + 64 * t];
        float4 b = x4[lane + 64 * t];
        acc += a.x * b.x + a.y * b.y + a.z * b.z + a.w * b.w;
    }
#pragma unroll
    for (int o = 32; o; o >>= 1) acc += __shfl_xor(acc, o, 64);
    if (lane == 0) {
        float p = 1.f / (1.f + expf(-(acc + pb[cell])));
        float e = excited[cell] * 0.95f + p * 0.05f;
        e = fminf(fmaxf(e, 0.f), 1.f);
        int las = (e > 0.5f) ? 1 : 0;
        lasing[cell] = las;
        if (las) atomicAdd(nlas, 1);
    }
}

// ---------------------------------------------------------------------------
// Kernel 2: rotate states by exp(i * 0.1 * phase_vel). 4 elems/thread.
__global__ __launch_bounds__(256) void k_rot(const float* __restrict__ cr,
                                             const float* __restrict__ ci,
                                             const float* __restrict__ pv,
                                             float2* __restrict__ rot) {
    int i = blockIdx.x * 256 + threadIdx.x;        // over N*H/4
    const float4* cr4 = (const float4*)cr;
    const float4* ci4 = (const float4*)ci;
    const float4* pv4 = (const float4*)pv;
    float4 a = cr4[i], b = ci4[i], t = pv4[i];
    float s0, c0, s1, c1, s2, c2, s3, c3;
    __sincosf(0.1f * t.x, &s0, &c0);
    __sincosf(0.1f * t.y, &s1, &c1);
    __sincosf(0.1f * t.z, &s2, &c2);
    __sincosf(0.1f * t.w, &s3, &c3);
    float4 o0 = make_float4(a.x * c0 - b.x * s0, a.x * s0 + b.x * c0,
                            a.y * c1 - b.y * s1, a.y * s1 + b.y * c1);
    float4 o1 = make_float4(a.z * c2 - b.z * s2, a.z * s2 + b.z * c2,
                            a.w * c3 - b.w * s3, a.w * s3 + b.w * c3);
    float4* r4 = (float4*)rot;
    r4[2 * i]     = o0;
    r4[2 * i + 1] = o1;
}

// ---------------------------------------------------------------------------
// Kernel 3: neighbor coupling + new_states + emission partials.
// One block per cell, 512 threads (one per h-channel).
// coupling*nb_state = ((s_i . s_nb)/(|s_i||s_nb|)) * s_nb  -- no atan2 needed.
__global__ __launch_bounds__(512) void k_coup(const float2* __restrict__ rot,
                                              const int* __restrict__ nbrs,
                                              const int* __restrict__ lasing,
                                              float2* __restrict__ nst,
                                              float* __restrict__ emis) {
    __shared__ int nb[KNB];
    __shared__ int las;
    int cell = blockIdx.x;
    int c = threadIdx.x;
    if (c < KNB) nb[c] = nbrs[cell * KNB + c];
    if (c == KNB) las = lasing[cell];
    __syncthreads();

    float2 s = rot[(size_t)cell * HID + c];
    float rinv = rsqrtf(s.x * s.x + s.y * s.y);
    float ar = 0.f, ai = 0.f;
#pragma unroll
    for (int t = 0; t < KNB; ++t) {
        float2 q = rot[(size_t)nb[t] * HID + c];
        float d = s.x * q.x + s.y * q.y;
        float qinv = rsqrtf(q.x * q.x + q.y * q.y);
        float w = d * rinv * qinv;                 // cos(ang_i - ang_nb)
        ar = fmaf(w, q.x, ar);
        ai = fmaf(w, q.y, ai);
    }
    // new = 0.7*s + (0.3*0.1/15) * sum
    float nr = 0.7f * s.x + 0.002f * ar;
    float ni = 0.7f * s.y + 0.002f * ai;
    nst[(size_t)cell * HID + c] = make_float2(nr, ni);
    if (las) {
        float* em = emis + (size_t)(cell & (NCOPY - 1)) * 1024;
        atomicAdd(em + c, nr);
        atomicAdd(em + 512 + c, ni);
    }
}

// ---------------------------------------------------------------------------
// Kernel 4: reduce emission copies; cavity_new; cavity_phase (OLD cavity).
__global__ __launch_bounds__(512) void k_cav(const float* __restrict__ emis,
                                             const int* __restrict__ nlas,
                                             const float* __restrict__ cavr,
                                             const float* __restrict__ cavi,
                                             float* __restrict__ cav) {
    int c = threadIdx.x;
    float er = 0.f, ei = 0.f;
    for (int k = 0; k < NCOPY; ++k) {
        er += emis[k * 1024 + c];
        ei += emis[k * 1024 + 512 + c];
    }
    int nl = *nlas;
    float cr = cavr[c], ci = cavi[c];
    float nr, ni;
    if (nl > 0) {
        float inv = 1.f / (float)(nl > 1 ? nl : 1);
        nr = 0.8f * cr + 0.2f * er * inv;
        ni = 0.8f * ci + 0.2f * ei * inv;
    } else {
        nr = cr;
        ni = ci;
    }
    cav[c] = nr;
    cav[512 + c] = ni;
    cav[1024 + c] = atan2f(ci, cr);                // old cavity phase
}

// ---------------------------------------------------------------------------
// Kernel 5: pred = [cav_new.re, cav_new.im] @ dec_W.T + dec_b. Wave per row.
__global__ __launch_bounds__(512) void k_pred(const float* __restrict__ cav,
                                              const float* __restrict__ dW,
                                              const float* __restrict__ db,
                                              float* __restrict__ out) {
    int gtid = blockIdx.x * 512 + threadIdx.x;
    int j = gtid >> 6;                             // 512 waves -> 512 outputs
    int lane = gtid & 63;
    const float4* w4 = (const float4*)(dW + (size_t)j * (2 * HID));
    const float4* o4 = (const float4*)cav;         // first 1024 floats = out_real
    float acc = 0.f;
#pragma unroll
    for (int t = 0; t < (2 * HID / 4) / 64; ++t) { // 4 iters
        float4 a = w4[lane + 64 * t];
        float4 b = o4[lane + 64 * t];
        acc += a.x * b.x + a.y * b.y + a.z * b.z + a.w * b.w;
    }
#pragma unroll
    for (int o = 32; o; o >>= 1) acc += __shfl_xor(acc, o, 64);
    if (lane == 0) out[j] = acc + db[j];
}

// ---------------------------------------------------------------------------
// Kernel 6: phase-lock lasing cells, add cavity feedback, row-max renorm,
// write per-cell (sum_a, sum_a2) partials. Block per cell. NO global atomics.
__global__ __launch_bounds__(512) void k_fin(const float2* __restrict__ nst,
                                             const int* __restrict__ lasing,
                                             const float* __restrict__ cav,
                                             float2* __restrict__ vpart) {
    __shared__ float sred[8];
    __shared__ float sbc;
    int cell = blockIdx.x;
    int c = threadIdx.x;
    int wid = c >> 6, lane = c & 63;
    int las = lasing[cell];

    float2 v = nst[(size_t)cell * HID + c];
    if (las) {
        float r = sqrtf(v.x * v.x + v.y * v.y);
        float ang = atan2f(v.y, v.x);
        float locked = 0.3f * cav[1024 + c] + 0.7f * ang;
        float sn, cs;
        __sincosf(locked, &sn, &cs);
        v = make_float2(r * cs, r * sn);
    }
    v.x += 0.05f * cav[c];
    v.y += 0.05f * cav[512 + c];
    float amp = sqrtf(v.x * v.x + v.y * v.y);

    // block max
    float m = amp;
#pragma unroll
    for (int o = 32; o; o >>= 1) m = fmaxf(m, __shfl_xor(m, o, 64));
    if (lane == 0) sred[wid] = m;
    __syncthreads();
    if (c == 0) {
        float mm = sred[0];
        for (int k = 1; k < 8; ++k) mm = fmaxf(mm, sred[k]);
        sbc = mm;
    }
    __syncthreads();
    float a = amp / (sbc + 1e-8f);

    // block sums of a and a^2
    float s1 = a, s2 = a * a;
#pragma unroll
    for (int o = 32; o; o >>= 1) { s1 += __shfl_xor(s1, o, 64); s2 += __shfl_xor(s2, o, 64); }
    __shared__ float w1[8], w2[8];
    if (lane == 0) { w1[wid] = s1; w2[wid] = s2; }
    __syncthreads();
    if (c == 0) {
        float t1 = 0.f, t2 = 0.f;
        for (int k = 0; k < 8; ++k) { t1 += w1[k]; t2 += w2[k]; }
        vpart[cell] = make_float2(t1, t2);         // contention-free store
    }
}

// ---------------------------------------------------------------------------
// Kernel 7: reduce per-cell partials (double accum); tension = E[a^2]-E[a]^2
__global__ __launch_bounds__(1024) void k_var(const float2* __restrict__ vpart,
                                              float* __restrict__ out) {
    __shared__ double l1[16], l2[16];
    int c = threadIdx.x;
    int wid = c >> 6, lane = c & 63;
    double s1 = 0.0, s2 = 0.0;
#pragma unroll
    for (int t = 0; t < N_CELLS / 1024; ++t) {     // 16 iters
        float2 p = vpart[c + 1024 * t];
        s1 += (double)p.x;
        s2 += (double)p.y;
    }
#pragma unroll
    for (int o = 32; o; o >>= 1) { s1 += __shfl_xor(s1, o, 64); s2 += __shfl_xor(s2, o, 64); }
    if (lane == 0) { l1[wid] = s1; l2[wid] = s2; }
    __syncthreads();
    if (c == 0) {
        double t1 = 0.0, t2 = 0.0;
        for (int k = 0; k < 16; ++k) { t1 += l1[k]; t2 += l2[k]; }
        double n = (double)N_CELLS * (double)HID;
        double mean = t1 / n;
        out[IND] = (float)(t2 / n - mean * mean);
    }
}

// ---------------------------------------------------------------------------
extern "C" void kernel_launch(void* const* d_in, const int* in_sizes, int n_in,
                              void* d_out, int out_size, void* d_ws, size_t ws_size,
                              hipStream_t stream) {
    const float* x       = (const float*)d_in[0];
    const float* pump_W  = (const float*)d_in[1];
    const float* pump_b  = (const float*)d_in[2];
    const float* dec_W   = (const float*)d_in[3];
    const float* dec_b   = (const float*)d_in[4];
    const float* cs_re   = (const float*)d_in[5];
    const float* cs_im   = (const float*)d_in[6];
    const float* excited = (const float*)d_in[7];
    const float* pvel    = (const float*)d_in[8];
    const float* cav_re  = (const float*)d_in[9];
    const float* cav_im  = (const float*)d_in[10];
    const int*   nbrs    = (const int*)d_in[11];

    float* out = (float*)d_out;
    char* ws = (char*)d_ws;
    int*    nlas  = (int*)(ws + NLAS_OFF);
    float*  emis  = (float*)(ws + EMIS_OFF);
    int*    lasv  = (int*)(ws + LAS_OFF);
    float*  cav   = (float*)(ws + CAV_OFF);
    float2* vpart = (float2*)(ws + VPART_OFF);
    float2* rot   = (float2*)(ws + ROT_OFF);
    float2* nst   = (float2*)(ws + NST_OFF);

    // zero nlas + emission accumulators (ws is poisoned 0xAA before every launch)
    hipMemsetAsync(ws, 0, EMIS_OFF + NCOPY * 1024 * 4, stream);

    k_pump<<<N_CELLS / 4, 256, 0, stream>>>(x, pump_W, pump_b, excited, lasv, nlas);
    k_rot<<<(N_CELLS * HID / 4) / 256, 256, 0, stream>>>(cs_re, cs_im, pvel, rot);
    k_coup<<<N_CELLS, 512, 0, stream>>>(rot, nbrs, lasv, nst, emis);
    k_cav<<<1, 512, 0, stream>>>(emis, nlas, cav_re, cav_im, cav);
    k_pred<<<64, 512, 0, stream>>>(cav, dec_W, dec_b, out);
    k_fin<<<N_CELLS, 512, 0, stream>>>(nst, lasv, cav, vpart);
    k_var<<<1, 1024, 0, stream>>>(vpart, out);
}